// Round 11
// baseline (541.117 us; speedup 1.0000x reference)
//
#include <hip/hip_runtime.h>

// MixingAttention on MI355X (gfx950) — ROUND 11.
// GEMM: double-buffered LDS (T3-minimum: stage t+1 issued before compute t,
// ONE barrier/iter) + f32->bf16 cast fused into proj A-staging via T14
// issue-early/write-late reg-staging (cast pass deleted).

using s16x8 = __attribute__((ext_vector_type(8))) short;   // 8 bf16
using f32x4 = __attribute__((ext_vector_type(4))) float;   // 4 f32 acc
typedef __attribute__((ext_vector_type(2))) unsigned u32x2;

#define NTOK 144
#define NHEADS 16
#define CDIM 512
#define TROWS 9216     // 64*144 template rows
#define SROWS 36864    // 256*144 search rows
#define TOTROWS 46080
#define NWIN 320
#define NCLS 20        // 4 (mask1) + 16 (mask0) mask classes

__device__ __forceinline__ unsigned short f2bf(float f) {
  unsigned u = __float_as_uint(f);
  u += 0x7fffu + ((u >> 16) & 1u);     // RNE
  return (unsigned short)(u >> 16);
}
__device__ __forceinline__ float bf2f(unsigned short u) {
  return __uint_as_float(((unsigned)u) << 16);
}
__device__ __forceinline__ s16x8 mk8(unsigned a, unsigned b, unsigned c, unsigned d) {
  union { unsigned u[4]; s16x8 v; } x;
  x.u[0] = a; x.u[1] = b; x.u[2] = c; x.u[3] = d;
  return x.v;
}

// async global->LDS, 16B per lane; lds base must be wave-uniform.
__device__ __forceinline__ void gld16(const unsigned short* g, short* l) {
  __builtin_amdgcn_global_load_lds(
      (const __attribute__((address_space(1))) unsigned int*)g,
      (__attribute__((address_space(3))) unsigned int*)l, 16, 0, 0);
}

// ---------------- prep kernels ----------------

__global__ void transpose_cast(const float* __restrict__ w,
                               unsigned short* __restrict__ wT, int Kd, int Nd) {
  int i = blockIdx.x * 256 + threadIdx.x;
  if (i >= Kd * Nd) return;
  int n = i / Kd, k = i % Kd;
  wT[i] = f2bf(w[(size_t)k * Nd + n]);
}

// cmb[cls][h][qi][kj] = rel-pos-bias(h,qi,kj) + mask(cls,qi,kj), bf16
__global__ void build_cmb(const float* __restrict__ rpb, const float* __restrict__ m0,
                          const float* __restrict__ m1, unsigned short* __restrict__ cmb) {
  int i = blockIdx.x * 256 + threadIdx.x;
  if (i >= NCLS * NHEADS * NTOK * NTOK) return;
  int cls = i / (NHEADS * NTOK * NTOK);
  int rem = i % (NHEADS * NTOK * NTOK);
  int h = rem / (NTOK * NTOK);
  int ij = rem % (NTOK * NTOK);
  int qi = ij / NTOK, kj = ij % NTOK;
  int dh = qi / 12 - kj / 12 + 11;
  int dw = qi % 12 - kj % 12 + 11;
  float bias = rpb[(dh * 23 + dw) * NHEADS + h];
  float mv = (cls < 4) ? m1[(size_t)cls * NTOK * NTOK + ij]
                       : m0[(size_t)(cls - 4) * NTOK * NTOK + ij];
  cmb[i] = f2bf(bias + mv);
}

// ---------------- MFMA GEMM: BK=64, XOR-swizzle, dbuf, 1 barrier/iter -------
// C(M,N) = A(M,K) @ B(K,N); per-row-block select: rows < TROWS use At/BTt/biast,
// else Asrch (row-rebased)/BTs/biass.
// AF32: A is f32, reg-staged (T14 split: load-early, cvt+ds_write late) into
//       swizzled LDS slots. Else A staged by global_load_lds from pre-swizzled
//       global cols (LDS dest linear).
// LDS slot (row, grp p) holds global col-group p ^ (row&7).
// EPI 0: +bias, bf16.  EPI 1: +bias, Q-scale cols<512, bf16.  EPI 2: +bias, f32.
template<int AF32, int EPI>
__global__ __launch_bounds__(256) void gemm_glds(
    const void* __restrict__ At, const void* __restrict__ Asrch,
    const unsigned short* __restrict__ BTt, const unsigned short* __restrict__ BTs,
    const float* __restrict__ biast, const float* __restrict__ biass,
    void* __restrict__ Cout, int M, int N, int K)
{
  __shared__ short As[2][128 * 64];   // 2 x 16KB
  __shared__ short Bs[2][128 * 64];   // 2 x 16KB
  const int t = threadIdx.x;
  const int lane = t & 63, wv = t >> 6, lg = lane >> 4, lc = lane & 15;
  const int bn = blockIdx.x * 128, bm = blockIdx.y * 128;   // N fastest
  const bool isT = bm < TROWS;
  const unsigned short* BT = isT ? BTt : BTs;
  const float* bias = isT ? biast : biass;

  // B staging (always gload_lds): rows 32wv+8i+(l>>3), pre-swizzled col group.
  const int srow = 32 * wv + (lane >> 3);
  const int scol = ((lane & 7) ^ ((lane >> 3) & 7)) * 8;
  const unsigned short* bSrc = BT + (size_t)(bn + srow) * K + scol;
  const size_t rowK8 = (size_t)8 * K;

  // A pointers (block row 0)
  const unsigned short* aB = nullptr;
  const float* aFrow = nullptr;
  if (AF32) {
    const float* aF = (const float*)(isT ? At : Asrch) + (size_t)(isT ? bm : bm - TROWS) * K;
    aFrow = aF + (size_t)(t >> 1) * K + (t & 1) * 32;   // this thread's row/half
  } else {
    aB = (const unsigned short*)(isT ? At : Asrch) + (size_t)(isT ? bm : bm - TROWS) * K;
  }
  const unsigned short* aSrc = AF32 ? nullptr : aB + (size_t)srow * K + scol;

  f32x4 acc[2][8] = {};
  float4 fr[8];                      // f32 A-tile regs (live across compute)

  auto LOADA = [&](int kt) {         // issue f32 loads (early)
#pragma unroll
    for (int j = 0; j < 4; j++) {
      fr[2 * j]     = *(const float4*)(aFrow + kt + j * 8);
      fr[2 * j + 1] = *(const float4*)(aFrow + kt + j * 8 + 4);
    }
  };
  auto STOREA = [&](int b) {         // cvt + ds_write to swizzled slots (late)
    const int r = t >> 1;
#pragma unroll
    for (int j = 0; j < 4; j++) {
      float4 f0 = fr[2 * j], f1 = fr[2 * j + 1];
      s16x8 o;
      o[0] = (short)f2bf(f0.x); o[1] = (short)f2bf(f0.y);
      o[2] = (short)f2bf(f0.z); o[3] = (short)f2bf(f0.w);
      o[4] = (short)f2bf(f1.x); o[5] = (short)f2bf(f1.y);
      o[6] = (short)f2bf(f1.z); o[7] = (short)f2bf(f1.w);
      const int g = (t & 1) * 4 + j;
      const int p = g ^ (r & 7);
      *(s16x8*)&As[b][r * 64 + p * 8] = o;
    }
  };
  auto STAGE = [&](int b, int kt) {  // gload_lds staging (B, and A when bf16)
#pragma unroll
    for (int i = 0; i < 4; i++) {
      if (!AF32) gld16(aSrc + kt + i * rowK8, &As[b][(wv * 4 + i) * 512]);
      gld16(bSrc + kt + i * rowK8, &Bs[b][(wv * 4 + i) * 512]);
    }
  };
  auto COMPUTE = [&](int b) {
#pragma unroll
    for (int kk = 0; kk < 2; kk++) {
      const int csw = 8 * ((4 * kk + lg) ^ (lc & 7));
      const int r0 = wv * 32 + lc, r1 = r0 + 16;
      s16x8 a0 = *(const s16x8*)&As[b][r0 * 64 + csw];
      s16x8 a1 = *(const s16x8*)&As[b][r1 * 64 + csw];
#pragma unroll
      for (int nt = 0; nt < 8; nt++) {
        s16x8 bfr = *(const s16x8*)&Bs[b][(nt * 16 + lc) * 64 + csw];
        acc[0][nt] = __builtin_amdgcn_mfma_f32_16x16x32_bf16(a0, bfr, acc[0][nt], 0, 0, 0);
        acc[1][nt] = __builtin_amdgcn_mfma_f32_16x16x32_bf16(a1, bfr, acc[1][nt], 0, 0, 0);
      }
    }
  };

  // prologue
  if (AF32) LOADA(0);
  STAGE(0, 0);
  if (AF32) STOREA(0);
  __syncthreads();

  int cur = 0;
  for (int kt = 64; kt < K; kt += 64) {
    if (AF32) LOADA(kt);        // issue next-tile f32 loads (latency hides under MFMA)
    STAGE(cur ^ 1, kt);         // fire-and-forget gload_lds into other buffer
    COMPUTE(cur);
    if (AF32) STOREA(cur ^ 1);  // waits the f32 loads, writes LDS
    __syncthreads();            // drains vmcnt+lgkm; other buffer ready
    cur ^= 1;
  }
  COMPUTE(cur);

#pragma unroll
  for (int mt = 0; mt < 2; mt++) {
    const int rbase = bm + wv * 32 + mt * 16 + lg * 4;
#pragma unroll
    for (int nt = 0; nt < 8; nt++) {
      const int cg = bn + nt * 16 + lc;
#pragma unroll
      for (int r = 0; r < 4; r++) {
        const int rg = rbase + r;
        float val = acc[mt][nt][r] + bias[cg];
        if (EPI == 2) {
          ((float*)Cout)[(size_t)rg * N + cg] = val;
        } else {
          if (EPI == 1 && cg < 512) val *= 0.17677669529663687f;   // Q scale
          ((unsigned short*)Cout)[(size_t)rg * N + cg] = f2bf(val);
        }
      }
    }
  }
}

// ---------------- LayerNorm, in place, vectorized (wave per row) ----------------
__global__ __launch_bounds__(256) void ln_kernel(
    unsigned short* __restrict__ xa,
    const float* __restrict__ g_pt, const float* __restrict__ be_pt,
    const float* __restrict__ g_ps, const float* __restrict__ be_ps)
{
  const int row = blockIdx.x * 4 + (threadIdx.x >> 6);
  const int lane = threadIdx.x & 63;
  const bool isT = row < TROWS;
  const float* gg = isT ? g_pt : g_ps;
  const float* be = isT ? be_pt : be_ps;
  unsigned short* p = xa + (size_t)row * CDIM;
  const int c0 = lane * 8;

  s16x8 v8 = *(const s16x8*)&p[c0];
  float f[8];
  float s = 0.f, s2 = 0.f;
#pragma unroll
  for (int i = 0; i < 8; i++) {
    float xv = bf2f((unsigned short)v8[i]);
    f[i] = xv; s += xv; s2 += xv * xv;
  }
#pragma unroll
  for (int d = 1; d < 64; d <<= 1) { s += __shfl_xor(s, d); s2 += __shfl_xor(s2, d); }
  float mu = s * (1.f / CDIM);
  float var = s2 * (1.f / CDIM) - mu * mu;
  float rs = rsqrtf(var + 1e-5f);

  float4 g0 = *(const float4*)&gg[c0], g1 = *(const float4*)&gg[c0 + 4];
  float4 e0 = *(const float4*)&be[c0], e1 = *(const float4*)&be[c0 + 4];
  float gv[8] = {g0.x, g0.y, g0.z, g0.w, g1.x, g1.y, g1.z, g1.w};
  float ev[8] = {e0.x, e0.y, e0.z, e0.w, e1.x, e1.y, e1.z, e1.w};
  s16x8 o;
#pragma unroll
  for (int i = 0; i < 8; i++)
    o[i] = (short)f2bf((f[i] - mu) * rs * gv[i] + ev[i]);
  *(s16x8*)&p[c0] = o;
}

// ---------------- fused attention, swapped-operand, one block per (w,h) ------
__global__ __launch_bounds__(576) void attn_kernel(
    const unsigned short* __restrict__ qkv, const unsigned short* __restrict__ cmb,
    unsigned short* __restrict__ outp)
{
  __shared__ short VT[32 * 168];    // VT[d][key], keys 144..159 zeroed
  const int w = blockIdx.x >> 4, h = blockIdx.x & 15;
  const int t = threadIdx.x;
  const unsigned short* qb = qkv + (size_t)w * NTOK * 1536;
  const int hq = h * 32;

  {  // stage V transposed
    const int n = t >> 2, d0 = (t & 3) * 8;
    s16x8 vv = *(const s16x8*)&qb[(size_t)n * 1536 + 1024 + hq + d0];
#pragma unroll
    for (int i = 0; i < 8; i++) VT[(d0 + i) * 168 + n] = vv[i];
  }
  if (t < 512) VT[(t >> 4) * 168 + 144 + (t & 15)] = 0;
  __syncthreads();

  const int lane = t & 63, wv = t >> 6, lg = lane >> 4, lc = lane & 15;
  const int q = wv * 16 + lc;           // this lane's query row (window-local)
  const f32x4 zero = {0.f, 0.f, 0.f, 0.f};

  const s16x8 qf = *(const s16x8*)&qb[(size_t)q * 1536 + hq + lg * 8];

  const int cls = (w < 64) ? (w & 3) : 4 + ((w - 64) & 15);
  const unsigned short* cm =
      cmb + ((size_t)cls * NHEADS + h) * (NTOK * NTOK) + (size_t)q * NTOK;
  uint2 cmr[9];
#pragma unroll
  for (int nt = 0; nt < 9; nt++)
    cmr[nt] = *(const uint2*)&cm[nt * 16 + lg * 4];

  f32x4 accS[9];
#pragma unroll
  for (int nt = 0; nt < 9; nt++) {
    s16x8 kf = *(const s16x8*)&qb[(size_t)(nt * 16 + lc) * 1536 + 512 + hq + lg * 8];
    accS[nt] = __builtin_amdgcn_mfma_f32_16x16x32_bf16(kf, qf, zero, 0, 0, 0);
  }

  float mx = -1e30f;
#pragma unroll
  for (int nt = 0; nt < 9; nt++) {
    accS[nt][0] += bf2f((unsigned short)(cmr[nt].x & 0xffff));
    accS[nt][1] += bf2f((unsigned short)(cmr[nt].x >> 16));
    accS[nt][2] += bf2f((unsigned short)(cmr[nt].y & 0xffff));
    accS[nt][3] += bf2f((unsigned short)(cmr[nt].y >> 16));
#pragma unroll
    for (int r = 0; r < 4; r++) mx = fmaxf(mx, accS[nt][r]);
  }
  mx = fmaxf(mx, __shfl_xor(mx, 16));
  mx = fmaxf(mx, __shfl_xor(mx, 32));

  float sum = 0.f;
#pragma unroll
  for (int nt = 0; nt < 9; nt++)
#pragma unroll
    for (int r = 0; r < 4; r++) {
      float e = __expf(accS[nt][r] - mx);
      accS[nt][r] = e;
      sum += e;
    }
  sum += __shfl_xor(sum, 16);
  sum += __shfl_xor(sum, 32);
  const float inv = 1.f / sum;

  unsigned pk0[9], pk1[9];
#pragma unroll
  for (int nt = 0; nt < 9; nt++) {
    pk0[nt] = (unsigned)f2bf(accS[nt][0]) | ((unsigned)f2bf(accS[nt][1]) << 16);
    pk1[nt] = (unsigned)f2bf(accS[nt][2]) | ((unsigned)f2bf(accS[nt][3]) << 16);
  }

#pragma unroll
  for (int dt = 0; dt < 2; dt++) {
    const short* vbase = &VT[(dt * 16 + lc) * 168];
    f32x4 accO = zero;
#pragma unroll
    for (int kk = 0; kk < 4; kk++) {
      u32x2 A0 = *(const u32x2*)&vbase[32 * kk + lg * 4];
      u32x2 A1 = *(const u32x2*)&vbase[32 * kk + 16 + lg * 4];
      s16x8 a = mk8(A0[0], A0[1], A1[0], A1[1]);
      s16x8 b = mk8(pk0[2 * kk], pk1[2 * kk], pk0[2 * kk + 1], pk1[2 * kk + 1]);
      accO = __builtin_amdgcn_mfma_f32_16x16x32_bf16(a, b, accO, 0, 0, 0);
    }
    {
      u32x2 A0 = *(const u32x2*)&vbase[128 + lg * 4];
      s16x8 a = mk8(A0[0], A0[1], 0u, 0u);
      s16x8 b = mk8(pk0[8], pk1[8], 0u, 0u);
      accO = __builtin_amdgcn_mfma_f32_16x16x32_bf16(a, b, accO, 0, 0, 0);
    }
    unsigned o0 = (unsigned)f2bf(accO[0] * inv) | ((unsigned)f2bf(accO[1] * inv) << 16);
    unsigned o1 = (unsigned)f2bf(accO[2] * inv) | ((unsigned)f2bf(accO[3] * inv) << 16);
    uint2 st; st.x = o0; st.y = o1;
    *(uint2*)&outp[(size_t)(w * NTOK + q) * CDIM + hq + dt * 16 + lg * 4] = st;
  }
}

// ---------------- launch ----------------
extern "C" void kernel_launch(void* const* d_in, const int* in_sizes, int n_in,
                              void* d_out, int out_size, void* d_ws, size_t ws_size,
                              hipStream_t stream)
{
  const float* x     = (const float*)d_in[0];
  const float* tpl   = (const float*)d_in[1];
  const float* mask0 = (const float*)d_in[2];
  const float* mask1 = (const float*)d_in[3];
  const float* rpb   = (const float*)d_in[8];
  const float* w_ps  = (const float*)d_in[9];
  const float* b_ps  = (const float*)d_in[10];
  const float* g_ps  = (const float*)d_in[11];
  const float* be_ps = (const float*)d_in[12];
  const float* w_pt  = (const float*)d_in[13];
  const float* b_pt  = (const float*)d_in[14];
  const float* g_pt  = (const float*)d_in[15];
  const float* be_pt = (const float*)d_in[16];
  const float* w_qkv = (const float*)d_in[17];
  const float* b_qkv = (const float*)d_in[18];
  const float* w_tr  = (const float*)d_in[19];
  const float* b_tr  = (const float*)d_in[20];
  const float* w_sr  = (const float*)d_in[21];
  const float* b_sr  = (const float*)d_in[22];

  // ws layout (~208MB of 720MiB):
  char* ws = (char*)d_ws;
  unsigned short* wpsT  = (unsigned short*)(ws + 0x0000000);  // 1MB
  unsigned short* wptT  = (unsigned short*)(ws + 0x0100000);  // 1MB
  unsigned short* wqkvT = (unsigned short*)(ws + 0x0200000);  // 1.5MB
  unsigned short* wtrT  = (unsigned short*)(ws + 0x0380000);  // 1MB
  unsigned short* wsrT  = (unsigned short*)(ws + 0x0480000);  // 1MB
  unsigned short* cmb   = (unsigned short*)(ws + 0x0580000);  // 12.7MB
  unsigned short* xa    = (unsigned short*)(ws + 0x1300000);  // 47.2MB [46080][512]
  unsigned short* qkvF  = (unsigned short*)(ws + 0x4000000);  // 141.6MB [46080][1536]
  float* outb           = (float*)d_out;

  transpose_cast<<<2048, 256, 0, stream>>>(w_ps, wpsT, 1024, 512);
  transpose_cast<<<2048, 256, 0, stream>>>(w_pt, wptT, 1024, 512);
  transpose_cast<<<3072, 256, 0, stream>>>(w_qkv, wqkvT, 512, 1536);
  transpose_cast<<<2048, 256, 0, stream>>>(w_tr, wtrT, 512, 1024);
  transpose_cast<<<2048, 256, 0, stream>>>(w_sr, wsrT, 512, 1024);
  build_cmb<<<(NCLS * NHEADS * NTOK * NTOK + 255) / 256, 256, 0, stream>>>(rpb, mask0, mask1, cmb);

  // projection GEMM (merged, f32 A fused-cast) -> xa bf16   [grid: N fastest]
  gemm_glds<1, 0><<<dim3(4, 360), 256, 0, stream>>>(tpl, x, wptT, wpsT, b_pt, b_ps,
                                                    xa, TOTROWS, CDIM, 1024);
  // LayerNorm in place on xa
  ln_kernel<<<TOTROWS / 4, 256, 0, stream>>>(xa, g_pt, be_pt, g_ps, be_ps);

  // QKV GEMM (one dispatch) -> qkvF
  gemm_glds<0, 1><<<dim3(12, 360), 256, 0, stream>>>(
      xa, xa + (size_t)TROWS * CDIM, wqkvT, wqkvT, b_qkv, b_qkv,
      qkvF, TOTROWS, 1536, CDIM);
  // fused attention (one dispatch) -> xa
  attn_kernel<<<NWIN * NHEADS, 576, 0, stream>>>(qkvF, cmb, xa);

  // output GEMM (merged) -> d_out f32
  gemm_glds<0, 2><<<dim3(8, 360), 256, 0, stream>>>(
      xa, xa + (size_t)TROWS * CDIM, wtrT, wsrT, b_tr, b_sr,
      outb, TOTROWS, 1024, CDIM);
}

// Round 13
// 499.184 us; speedup vs baseline: 1.0840x; 1.0840x over previous
//
#include <hip/hip_runtime.h>

// MixingAttention on MI355X (gfx950) — ROUND 13.
// r12 bug: bqS overlapped wsrT (clobbered w_sr cols 960-966 -> Output 1 fail).
// Fixed bqS offset (0x12F0000). Logic identical to r12: r10 GEMM core +
// T1 chunked XCD swizzle + Q-scale folded into QKV weights/bias.

using s16x8 = __attribute__((ext_vector_type(8))) short;   // 8 bf16
using f32x4 = __attribute__((ext_vector_type(4))) float;   // 4 f32 acc
typedef __attribute__((ext_vector_type(2))) unsigned u32x2;

#define NTOK 144
#define NHEADS 16
#define CDIM 512
#define TROWS 9216     // 64*144 template rows
#define SROWS 36864    // 256*144 search rows
#define TOTROWS 46080
#define NWIN 320
#define NCLS 20        // 4 (mask1) + 16 (mask0) mask classes

__device__ __forceinline__ unsigned short f2bf(float f) {
  unsigned u = __float_as_uint(f);
  u += 0x7fffu + ((u >> 16) & 1u);     // RNE
  return (unsigned short)(u >> 16);
}
__device__ __forceinline__ float bf2f(unsigned short u) {
  return __uint_as_float(((unsigned)u) << 16);
}
__device__ __forceinline__ s16x8 mk8(unsigned a, unsigned b, unsigned c, unsigned d) {
  union { unsigned u[4]; s16x8 v; } x;
  x.u[0] = a; x.u[1] = b; x.u[2] = c; x.u[3] = d;
  return x.v;
}

// async global->LDS, 16B per lane; lds base must be wave-uniform.
__device__ __forceinline__ void gld16(const unsigned short* g, short* l) {
  __builtin_amdgcn_global_load_lds(
      (const __attribute__((address_space(1))) unsigned int*)g,
      (__attribute__((address_space(3))) unsigned int*)l, 16, 0, 0);
}

// ---------------- prep kernels ----------------

// w: (Kd, Nd) f32 row-major -> wT: (Nd, Kd) bf16; cols n < nScale scaled by s.
__global__ void transpose_cast(const float* __restrict__ w,
                               unsigned short* __restrict__ wT, int Kd, int Nd,
                               int nScale, float s) {
  int i = blockIdx.x * 256 + threadIdx.x;
  if (i >= Kd * Nd) return;
  int n = i / Kd, k = i % Kd;
  float v = w[(size_t)k * Nd + n];
  if (n < nScale) v *= s;
  wT[i] = f2bf(v);
}

// bq[i] = b_qkv[i] * (i<512 ? s : 1)
__global__ void scale_bias(const float* __restrict__ in, float* __restrict__ out) {
  int i = blockIdx.x * 256 + threadIdx.x;
  if (i >= 1536) return;
  out[i] = in[i] * (i < 512 ? 0.17677669529663687f : 1.0f);
}

// f32 -> bf16 bulk cast, 8 elems/thread
__global__ __launch_bounds__(256) void cast_bf16(const float* __restrict__ in,
                                                 unsigned short* __restrict__ out, int n8) {
  int i = blockIdx.x * 256 + threadIdx.x;
  if (i >= n8) return;
  const float4* p = (const float4*)in + (size_t)i * 2;
  float4 f0 = p[0], f1 = p[1];
  s16x8 o;
  o[0] = (short)f2bf(f0.x); o[1] = (short)f2bf(f0.y);
  o[2] = (short)f2bf(f0.z); o[3] = (short)f2bf(f0.w);
  o[4] = (short)f2bf(f1.x); o[5] = (short)f2bf(f1.y);
  o[6] = (short)f2bf(f1.z); o[7] = (short)f2bf(f1.w);
  *(s16x8*)&out[(size_t)i * 8] = o;
}

// cmb[cls][h][qi][kj] = rel-pos-bias(h,qi,kj) + mask(cls,qi,kj), bf16
__global__ void build_cmb(const float* __restrict__ rpb, const float* __restrict__ m0,
                          const float* __restrict__ m1, unsigned short* __restrict__ cmb) {
  int i = blockIdx.x * 256 + threadIdx.x;
  if (i >= NCLS * NHEADS * NTOK * NTOK) return;
  int cls = i / (NHEADS * NTOK * NTOK);
  int rem = i % (NHEADS * NTOK * NTOK);
  int h = rem / (NTOK * NTOK);
  int ij = rem % (NTOK * NTOK);
  int qi = ij / NTOK, kj = ij % NTOK;
  int dh = qi / 12 - kj / 12 + 11;
  int dw = qi % 12 - kj % 12 + 11;
  float bias = rpb[(dh * 23 + dw) * NHEADS + h];
  float mv = (cls < 4) ? m1[(size_t)cls * NTOK * NTOK + ij]
                       : m0[(size_t)(cls - 4) * NTOK * NTOK + ij];
  cmb[i] = f2bf(bias + mv);
}

// ---------------- MFMA GEMM: BK=64, XOR-swizzle, glds, XCD-chunked ----------
// C(M,N) = A(M,K) @ B(K,N); per-row-block select: rows < TROWS use BTt/biast.
// LDS slot (row, grp p) holds global col-group p ^ (row&7) (pre-swizzled src).
// Grid: dim3(N/128, M/128); logical id XCD-chunked so blocks sharing an
// A-panel run on ONE XCD (nb divisible by 8 for all our grids).
// EPI 0: +bias, bf16.  EPI 2: +bias, f32.
template<int EPI>
__global__ __launch_bounds__(256) void gemm_glds(
    const unsigned short* __restrict__ Ab,
    const unsigned short* __restrict__ BTt, const unsigned short* __restrict__ BTs,
    const float* __restrict__ biast, const float* __restrict__ biass,
    void* __restrict__ Cout, int M, int N, int K)
{
  __shared__ short As[128 * 64];   // 16KB
  __shared__ short Bs[128 * 64];   // 16KB
  const int t = threadIdx.x;
  const int lane = t & 63, wv = t >> 6, lg = lane >> 4, lc = lane & 15;

  // T1 chunked XCD swizzle (bijective: nb % 8 == 0 for all grids here)
  const int id = blockIdx.x + gridDim.x * blockIdx.y;
  const int chunk = (gridDim.x * gridDim.y) >> 3;
  const int lid = (id & 7) * chunk + (id >> 3);
  const int bn = (lid % gridDim.x) * 128, bm = (lid / gridDim.x) * 128;

  const bool isT = bm < TROWS;
  const unsigned short* BT = isT ? BTt : BTs;
  const float* bias = isT ? biast : biass;

  // staging: rows 32wv+8i+(l>>3), global col-group (l&7)^((l>>3)&7).
  const int srow = 32 * wv + (lane >> 3);
  const int scol = ((lane & 7) ^ ((lane >> 3) & 7)) * 8;
  const unsigned short* aSrc = Ab + (size_t)(bm + srow) * K + scol;
  const unsigned short* bSrc = BT + (size_t)(bn + srow) * K + scol;
  const size_t rowK8 = (size_t)8 * K;

  f32x4 acc[2][8] = {};

  for (int kt = 0; kt < K; kt += 64) {
    __syncthreads();
#pragma unroll
    for (int i = 0; i < 4; i++) {
      gld16(aSrc + kt + i * rowK8, &As[(wv * 4 + i) * 512]);
      gld16(bSrc + kt + i * rowK8, &Bs[(wv * 4 + i) * 512]);
    }
    __syncthreads();
#pragma unroll
    for (int kk = 0; kk < 2; kk++) {
      const int csw = 8 * ((4 * kk + lg) ^ (lc & 7));
      const int r0 = wv * 32 + lc, r1 = r0 + 16;
      s16x8 a0 = *(const s16x8*)&As[r0 * 64 + csw];
      s16x8 a1 = *(const s16x8*)&As[r1 * 64 + csw];
#pragma unroll
      for (int nt = 0; nt < 8; nt++) {
        s16x8 bfr = *(const s16x8*)&Bs[(nt * 16 + lc) * 64 + csw];
        acc[0][nt] = __builtin_amdgcn_mfma_f32_16x16x32_bf16(a0, bfr, acc[0][nt], 0, 0, 0);
        acc[1][nt] = __builtin_amdgcn_mfma_f32_16x16x32_bf16(a1, bfr, acc[1][nt], 0, 0, 0);
      }
    }
  }

#pragma unroll
  for (int mt = 0; mt < 2; mt++) {
    const int rbase = bm + wv * 32 + mt * 16 + lg * 4;
#pragma unroll
    for (int nt = 0; nt < 8; nt++) {
      const int cg = bn + nt * 16 + lc;
#pragma unroll
      for (int r = 0; r < 4; r++) {
        const int rg = rbase + r;
        float val = acc[mt][nt][r] + bias[cg];
        if (EPI == 2) {
          ((float*)Cout)[(size_t)rg * N + cg] = val;
        } else {
          ((unsigned short*)Cout)[(size_t)rg * N + cg] = f2bf(val);
        }
      }
    }
  }
}

// ---------------- LayerNorm, in place, vectorized (wave per row) ----------------
__global__ __launch_bounds__(256) void ln_kernel(
    unsigned short* __restrict__ xa,
    const float* __restrict__ g_pt, const float* __restrict__ be_pt,
    const float* __restrict__ g_ps, const float* __restrict__ be_ps)
{
  const int row = blockIdx.x * 4 + (threadIdx.x >> 6);
  const int lane = threadIdx.x & 63;
  const bool isT = row < TROWS;
  const float* gg = isT ? g_pt : g_ps;
  const float* be = isT ? be_pt : be_ps;
  unsigned short* p = xa + (size_t)row * CDIM;
  const int c0 = lane * 8;

  s16x8 v8 = *(const s16x8*)&p[c0];
  float f[8];
  float s = 0.f, s2 = 0.f;
#pragma unroll
  for (int i = 0; i < 8; i++) {
    float xv = bf2f((unsigned short)v8[i]);
    f[i] = xv; s += xv; s2 += xv * xv;
  }
#pragma unroll
  for (int d = 1; d < 64; d <<= 1) { s += __shfl_xor(s, d); s2 += __shfl_xor(s2, d); }
  float mu = s * (1.f / CDIM);
  float var = s2 * (1.f / CDIM) - mu * mu;
  float rs = rsqrtf(var + 1e-5f);

  float4 g0 = *(const float4*)&gg[c0], g1 = *(const float4*)&gg[c0 + 4];
  float4 e0 = *(const float4*)&be[c0], e1 = *(const float4*)&be[c0 + 4];
  float gv[8] = {g0.x, g0.y, g0.z, g0.w, g1.x, g1.y, g1.z, g1.w};
  float ev[8] = {e0.x, e0.y, e0.z, e0.w, e1.x, e1.y, e1.z, e1.w};
  s16x8 o;
#pragma unroll
  for (int i = 0; i < 8; i++)
    o[i] = (short)f2bf((f[i] - mu) * rs * gv[i] + ev[i]);
  *(s16x8*)&p[c0] = o;
}

// ---------------- fused attention, swapped-operand, one block per (w,h) ------
__global__ __launch_bounds__(576) void attn_kernel(
    const unsigned short* __restrict__ qkv, const unsigned short* __restrict__ cmb,
    unsigned short* __restrict__ outp)
{
  __shared__ short VT[32 * 168];    // VT[d][key], keys 144..159 zeroed
  const int w = blockIdx.x >> 4, h = blockIdx.x & 15;
  const int t = threadIdx.x;
  const unsigned short* qb = qkv + (size_t)w * NTOK * 1536;
  const int hq = h * 32;

  {  // stage V transposed
    const int n = t >> 2, d0 = (t & 3) * 8;
    s16x8 vv = *(const s16x8*)&qb[(size_t)n * 1536 + 1024 + hq + d0];
#pragma unroll
    for (int i = 0; i < 8; i++) VT[(d0 + i) * 168 + n] = vv[i];
  }
  if (t < 512) VT[(t >> 4) * 168 + 144 + (t & 15)] = 0;
  __syncthreads();

  const int lane = t & 63, wv = t >> 6, lg = lane >> 4, lc = lane & 15;
  const int q = wv * 16 + lc;           // this lane's query row (window-local)
  const f32x4 zero = {0.f, 0.f, 0.f, 0.f};

  const s16x8 qf = *(const s16x8*)&qb[(size_t)q * 1536 + hq + lg * 8];

  const int cls = (w < 64) ? (w & 3) : 4 + ((w - 64) & 15);
  const unsigned short* cm =
      cmb + ((size_t)cls * NHEADS + h) * (NTOK * NTOK) + (size_t)q * NTOK;
  uint2 cmr[9];
#pragma unroll
  for (int nt = 0; nt < 9; nt++)
    cmr[nt] = *(const uint2*)&cm[nt * 16 + lg * 4];

  f32x4 accS[9];
#pragma unroll
  for (int nt = 0; nt < 9; nt++) {
    s16x8 kf = *(const s16x8*)&qb[(size_t)(nt * 16 + lc) * 1536 + 512 + hq + lg * 8];
    accS[nt] = __builtin_amdgcn_mfma_f32_16x16x32_bf16(kf, qf, zero, 0, 0, 0);
  }

  float mx = -1e30f;
#pragma unroll
  for (int nt = 0; nt < 9; nt++) {
    accS[nt][0] += bf2f((unsigned short)(cmr[nt].x & 0xffff));
    accS[nt][1] += bf2f((unsigned short)(cmr[nt].x >> 16));
    accS[nt][2] += bf2f((unsigned short)(cmr[nt].y & 0xffff));
    accS[nt][3] += bf2f((unsigned short)(cmr[nt].y >> 16));
#pragma unroll
    for (int r = 0; r < 4; r++) mx = fmaxf(mx, accS[nt][r]);
  }
  mx = fmaxf(mx, __shfl_xor(mx, 16));
  mx = fmaxf(mx, __shfl_xor(mx, 32));

  float sum = 0.f;
#pragma unroll
  for (int nt = 0; nt < 9; nt++)
#pragma unroll
    for (int r = 0; r < 4; r++) {
      float e = __expf(accS[nt][r] - mx);
      accS[nt][r] = e;
      sum += e;
    }
  sum += __shfl_xor(sum, 16);
  sum += __shfl_xor(sum, 32);
  const float inv = 1.f / sum;

  unsigned pk0[9], pk1[9];
#pragma unroll
  for (int nt = 0; nt < 9; nt++) {
    pk0[nt] = (unsigned)f2bf(accS[nt][0]) | ((unsigned)f2bf(accS[nt][1]) << 16);
    pk1[nt] = (unsigned)f2bf(accS[nt][2]) | ((unsigned)f2bf(accS[nt][3]) << 16);
  }

#pragma unroll
  for (int dt = 0; dt < 2; dt++) {
    const short* vbase = &VT[(dt * 16 + lc) * 168];
    f32x4 accO = zero;
#pragma unroll
    for (int kk = 0; kk < 4; kk++) {
      u32x2 A0 = *(const u32x2*)&vbase[32 * kk + lg * 4];
      u32x2 A1 = *(const u32x2*)&vbase[32 * kk + 16 + lg * 4];
      s16x8 a = mk8(A0[0], A0[1], A1[0], A1[1]);
      s16x8 b = mk8(pk0[2 * kk], pk1[2 * kk], pk0[2 * kk + 1], pk1[2 * kk + 1]);
      accO = __builtin_amdgcn_mfma_f32_16x16x32_bf16(a, b, accO, 0, 0, 0);
    }
    {
      u32x2 A0 = *(const u32x2*)&vbase[128 + lg * 4];
      s16x8 a = mk8(A0[0], A0[1], 0u, 0u);
      s16x8 b = mk8(pk0[8], pk1[8], 0u, 0u);
      accO = __builtin_amdgcn_mfma_f32_16x16x32_bf16(a, b, accO, 0, 0, 0);
    }
    unsigned o0 = (unsigned)f2bf(accO[0] * inv) | ((unsigned)f2bf(accO[1] * inv) << 16);
    unsigned o1 = (unsigned)f2bf(accO[2] * inv) | ((unsigned)f2bf(accO[3] * inv) << 16);
    uint2 st; st.x = o0; st.y = o1;
    *(uint2*)&outp[(size_t)(w * NTOK + q) * CDIM + hq + dt * 16 + lg * 4] = st;
  }
}

// ---------------- launch ----------------
extern "C" void kernel_launch(void* const* d_in, const int* in_sizes, int n_in,
                              void* d_out, int out_size, void* d_ws, size_t ws_size,
                              hipStream_t stream)
{
  const float* x     = (const float*)d_in[0];
  const float* tpl   = (const float*)d_in[1];
  const float* mask0 = (const float*)d_in[2];
  const float* mask1 = (const float*)d_in[3];
  const float* rpb   = (const float*)d_in[8];
  const float* w_ps  = (const float*)d_in[9];
  const float* b_ps  = (const float*)d_in[10];
  const float* g_ps  = (const float*)d_in[11];
  const float* be_ps = (const float*)d_in[12];
  const float* w_pt  = (const float*)d_in[13];
  const float* b_pt  = (const float*)d_in[14];
  const float* g_pt  = (const float*)d_in[15];
  const float* be_pt = (const float*)d_in[16];
  const float* w_qkv = (const float*)d_in[17];
  const float* b_qkv = (const float*)d_in[18];
  const float* w_tr  = (const float*)d_in[19];
  const float* b_tr  = (const float*)d_in[20];
  const float* w_sr  = (const float*)d_in[21];
  const float* b_sr  = (const float*)d_in[22];

  // ws layout (~236MB of 720MiB):
  char* ws = (char*)d_ws;
  unsigned short* wpsT  = (unsigned short*)(ws + 0x0000000);  // 1MB
  unsigned short* wptT  = (unsigned short*)(ws + 0x0100000);  // 1MB
  unsigned short* wqkvT = (unsigned short*)(ws + 0x0200000);  // 1.5MB (Q-scaled)
  unsigned short* wtrT  = (unsigned short*)(ws + 0x0380000);  // 1MB
  unsigned short* wsrT  = (unsigned short*)(ws + 0x0480000);  // 1MB [0x480000,0x580000)
  unsigned short* cmb   = (unsigned short*)(ws + 0x0580000);  // 12.7MB -> ends ~0x1228000
  float* bqS            = (float*)(ws + 0x12F0000);           // 6KB scaled b_qkv (free gap)
  unsigned short* xa    = (unsigned short*)(ws + 0x1300000);  // 47.2MB [46080][512]
  unsigned short* Sa    = (unsigned short*)(ws + 0x4000000);  // 94.4MB cast-A (union
  unsigned short* qkvF  = (unsigned short*)(ws + 0x4000000);  //  w/ 141.6MB qkv)
  float* outb           = (float*)d_out;

  transpose_cast<<<2048, 256, 0, stream>>>(w_ps, wpsT, 1024, 512, 0, 1.f);
  transpose_cast<<<2048, 256, 0, stream>>>(w_pt, wptT, 1024, 512, 0, 1.f);
  transpose_cast<<<3072, 256, 0, stream>>>(w_qkv, wqkvT, 512, 1536,
                                           512, 0.17677669529663687f);
  transpose_cast<<<2048, 256, 0, stream>>>(w_tr, wtrT, 512, 1024, 0, 1.f);
  transpose_cast<<<2048, 256, 0, stream>>>(w_sr, wsrT, 512, 1024, 0, 1.f);
  scale_bias<<<6, 256, 0, stream>>>(b_qkv, bqS);
  build_cmb<<<(NCLS * NHEADS * NTOK * NTOK + 255) / 256, 256, 0, stream>>>(rpb, mask0, mask1, cmb);

  // cast inputs to bf16: tpl -> Sa[0:9216), x -> Sa[9216:46080)
  cast_bf16<<<(TROWS * 1024 / 8 + 255) / 256, 256, 0, stream>>>(tpl, Sa, TROWS * 1024 / 8);
  cast_bf16<<<(SROWS * 1024 / 8 + 255) / 256, 256, 0, stream>>>(
      x, Sa + (size_t)TROWS * 1024, SROWS * 1024 / 8);

  // projection GEMM (merged template+search) -> xa bf16
  gemm_glds<0><<<dim3(4, 360), 256, 0, stream>>>(Sa, wptT, wpsT, b_pt, b_ps,
                                                 xa, TOTROWS, CDIM, 1024);
  // LayerNorm in place on xa
  ln_kernel<<<TOTROWS / 4, 256, 0, stream>>>(xa, g_pt, be_pt, g_ps, be_ps);

  // QKV GEMM (Q-scale folded into weights/bias) -> qkvF (overwrites dead Sa)
  gemm_glds<0><<<dim3(12, 360), 256, 0, stream>>>(xa, wqkvT, wqkvT, bqS, bqS,
                                                  qkvF, TOTROWS, 1536, CDIM);
  // fused attention (one dispatch) -> xa
  attn_kernel<<<NWIN * NHEADS, 576, 0, stream>>>(qkvF, cmb, xa);

  // output GEMM (merged) -> d_out f32
  gemm_glds<2><<<dim3(8, 360), 256, 0, stream>>>(xa, wtrT, wsrT, b_tr, b_sr,
                                                 outb, TOTROWS, 1024, CDIM);
}

// Round 14
// 472.587 us; speedup vs baseline: 1.1450x; 1.0563x over previous
//
#include <hip/hip_runtime.h>

// MixingAttention on MI355X (gfx950) — ROUND 14.
// GEMM: dbuf K-loop (STAGE(next) -> COMPUTE(cur) -> barrier; vmcnt drain
// overlaps compute) on top of r13's XCD swizzle. r11 decomposition showed
// dbuf helped bf16 GEMMs; only the AF32 fused-cast regressed (not re-added).
// Attn: barrier moved to just before PV (QK/softmax don't read VT);
// chunked XCD swizzle (16 heads of a window share one qkv panel).

using s16x8 = __attribute__((ext_vector_type(8))) short;   // 8 bf16
using f32x4 = __attribute__((ext_vector_type(4))) float;   // 4 f32 acc
typedef __attribute__((ext_vector_type(2))) unsigned u32x2;

#define NTOK 144
#define NHEADS 16
#define CDIM 512
#define TROWS 9216     // 64*144 template rows
#define SROWS 36864    // 256*144 search rows
#define TOTROWS 46080
#define NWIN 320
#define NCLS 20        // 4 (mask1) + 16 (mask0) mask classes

__device__ __forceinline__ unsigned short f2bf(float f) {
  unsigned u = __float_as_uint(f);
  u += 0x7fffu + ((u >> 16) & 1u);     // RNE
  return (unsigned short)(u >> 16);
}
__device__ __forceinline__ float bf2f(unsigned short u) {
  return __uint_as_float(((unsigned)u) << 16);
}
__device__ __forceinline__ s16x8 mk8(unsigned a, unsigned b, unsigned c, unsigned d) {
  union { unsigned u[4]; s16x8 v; } x;
  x.u[0] = a; x.u[1] = b; x.u[2] = c; x.u[3] = d;
  return x.v;
}

// async global->LDS, 16B per lane; lds base must be wave-uniform.
__device__ __forceinline__ void gld16(const unsigned short* g, short* l) {
  __builtin_amdgcn_global_load_lds(
      (const __attribute__((address_space(1))) unsigned int*)g,
      (__attribute__((address_space(3))) unsigned int*)l, 16, 0, 0);
}

// ---------------- prep kernels ----------------

// w: (Kd, Nd) f32 row-major -> wT: (Nd, Kd) bf16; cols n < nScale scaled by s.
__global__ void transpose_cast(const float* __restrict__ w,
                               unsigned short* __restrict__ wT, int Kd, int Nd,
                               int nScale, float s) {
  int i = blockIdx.x * 256 + threadIdx.x;
  if (i >= Kd * Nd) return;
  int n = i / Kd, k = i % Kd;
  float v = w[(size_t)k * Nd + n];
  if (n < nScale) v *= s;
  wT[i] = f2bf(v);
}

// bq[i] = b_qkv[i] * (i<512 ? s : 1)
__global__ void scale_bias(const float* __restrict__ in, float* __restrict__ out) {
  int i = blockIdx.x * 256 + threadIdx.x;
  if (i >= 1536) return;
  out[i] = in[i] * (i < 512 ? 0.17677669529663687f : 1.0f);
}

// f32 -> bf16 bulk cast, 8 elems/thread
__global__ __launch_bounds__(256) void cast_bf16(const float* __restrict__ in,
                                                 unsigned short* __restrict__ out, int n8) {
  int i = blockIdx.x * 256 + threadIdx.x;
  if (i >= n8) return;
  const float4* p = (const float4*)in + (size_t)i * 2;
  float4 f0 = p[0], f1 = p[1];
  s16x8 o;
  o[0] = (short)f2bf(f0.x); o[1] = (short)f2bf(f0.y);
  o[2] = (short)f2bf(f0.z); o[3] = (short)f2bf(f0.w);
  o[4] = (short)f2bf(f1.x); o[5] = (short)f2bf(f1.y);
  o[6] = (short)f2bf(f1.z); o[7] = (short)f2bf(f1.w);
  *(s16x8*)&out[(size_t)i * 8] = o;
}

// cmb[cls][h][qi][kj] = rel-pos-bias(h,qi,kj) + mask(cls,qi,kj), bf16
__global__ void build_cmb(const float* __restrict__ rpb, const float* __restrict__ m0,
                          const float* __restrict__ m1, unsigned short* __restrict__ cmb) {
  int i = blockIdx.x * 256 + threadIdx.x;
  if (i >= NCLS * NHEADS * NTOK * NTOK) return;
  int cls = i / (NHEADS * NTOK * NTOK);
  int rem = i % (NHEADS * NTOK * NTOK);
  int h = rem / (NTOK * NTOK);
  int ij = rem % (NTOK * NTOK);
  int qi = ij / NTOK, kj = ij % NTOK;
  int dh = qi / 12 - kj / 12 + 11;
  int dw = qi % 12 - kj % 12 + 11;
  float bias = rpb[(dh * 23 + dw) * NHEADS + h];
  float mv = (cls < 4) ? m1[(size_t)cls * NTOK * NTOK + ij]
                       : m0[(size_t)(cls - 4) * NTOK * NTOK + ij];
  cmb[i] = f2bf(bias + mv);
}

// ---------------- MFMA GEMM: BK=64, XOR-swizzle, glds, XCD-chunked, dbuf ----
// C(M,N) = A(M,K) @ B(K,N); per-row-block select: rows < TROWS use BTt/biast.
// LDS slot (row, grp p) holds global col-group p ^ (row&7) (pre-swizzled src).
// K-loop: STAGE(next buf) issued before COMPUTE(cur); ONE barrier per iter —
// the compiler's vmcnt-drain at the barrier lands after compute (overlap).
// EPI 0: +bias, bf16.  EPI 2: +bias, f32.
template<int EPI>
__global__ __launch_bounds__(256) void gemm_glds(
    const unsigned short* __restrict__ Ab,
    const unsigned short* __restrict__ BTt, const unsigned short* __restrict__ BTs,
    const float* __restrict__ biast, const float* __restrict__ biass,
    void* __restrict__ Cout, int M, int N, int K)
{
  __shared__ short As[2][128 * 64];   // 2 x 16KB
  __shared__ short Bs[2][128 * 64];   // 2 x 16KB
  const int t = threadIdx.x;
  const int lane = t & 63, wv = t >> 6, lg = lane >> 4, lc = lane & 15;

  // T1 chunked XCD swizzle (bijective: nb % 8 == 0 for all grids here)
  const int id = blockIdx.x + gridDim.x * blockIdx.y;
  const int chunk = (gridDim.x * gridDim.y) >> 3;
  const int lid = (id & 7) * chunk + (id >> 3);
  const int bn = (lid % gridDim.x) * 128, bm = (lid / gridDim.x) * 128;

  const bool isT = bm < TROWS;
  const unsigned short* BT = isT ? BTt : BTs;
  const float* bias = isT ? biast : biass;

  // staging: rows 32wv+8i+(l>>3), global col-group (l&7)^((l>>3)&7).
  const int srow = 32 * wv + (lane >> 3);
  const int scol = ((lane & 7) ^ ((lane >> 3) & 7)) * 8;
  const unsigned short* aSrc = Ab + (size_t)(bm + srow) * K + scol;
  const unsigned short* bSrc = BT + (size_t)(bn + srow) * K + scol;
  const size_t rowK8 = (size_t)8 * K;

  f32x4 acc[2][8] = {};

  auto STAGE = [&](int b, int kt) {
#pragma unroll
    for (int i = 0; i < 4; i++) {
      gld16(aSrc + kt + i * rowK8, &As[b][(wv * 4 + i) * 512]);
      gld16(bSrc + kt + i * rowK8, &Bs[b][(wv * 4 + i) * 512]);
    }
  };
  auto COMPUTE = [&](int b) {
#pragma unroll
    for (int kk = 0; kk < 2; kk++) {
      const int csw = 8 * ((4 * kk + lg) ^ (lc & 7));
      const int r0 = wv * 32 + lc, r1 = r0 + 16;
      s16x8 a0 = *(const s16x8*)&As[b][r0 * 64 + csw];
      s16x8 a1 = *(const s16x8*)&As[b][r1 * 64 + csw];
#pragma unroll
      for (int nt = 0; nt < 8; nt++) {
        s16x8 bfr = *(const s16x8*)&Bs[b][(nt * 16 + lc) * 64 + csw];
        acc[0][nt] = __builtin_amdgcn_mfma_f32_16x16x32_bf16(a0, bfr, acc[0][nt], 0, 0, 0);
        acc[1][nt] = __builtin_amdgcn_mfma_f32_16x16x32_bf16(a1, bfr, acc[1][nt], 0, 0, 0);
      }
    }
  };

  STAGE(0, 0);
  __syncthreads();
  int cur = 0;
  for (int kt = 64; kt < K; kt += 64) {
    STAGE(cur ^ 1, kt);   // fire-and-forget into other buffer
    COMPUTE(cur);         // overlaps with the loads in flight
    __syncthreads();      // drain (after compute) + cross-wave visibility
    cur ^= 1;
  }
  COMPUTE(cur);

#pragma unroll
  for (int mt = 0; mt < 2; mt++) {
    const int rbase = bm + wv * 32 + mt * 16 + lg * 4;
#pragma unroll
    for (int nt = 0; nt < 8; nt++) {
      const int cg = bn + nt * 16 + lc;
#pragma unroll
      for (int r = 0; r < 4; r++) {
        const int rg = rbase + r;
        float val = acc[mt][nt][r] + bias[cg];
        if (EPI == 2) {
          ((float*)Cout)[(size_t)rg * N + cg] = val;
        } else {
          ((unsigned short*)Cout)[(size_t)rg * N + cg] = f2bf(val);
        }
      }
    }
  }
}

// ---------------- LayerNorm, in place, vectorized (wave per row) ----------------
__global__ __launch_bounds__(256) void ln_kernel(
    unsigned short* __restrict__ xa,
    const float* __restrict__ g_pt, const float* __restrict__ be_pt,
    const float* __restrict__ g_ps, const float* __restrict__ be_ps)
{
  const int row = blockIdx.x * 4 + (threadIdx.x >> 6);
  const int lane = threadIdx.x & 63;
  const bool isT = row < TROWS;
  const float* gg = isT ? g_pt : g_ps;
  const float* be = isT ? be_pt : be_ps;
  unsigned short* p = xa + (size_t)row * CDIM;
  const int c0 = lane * 8;

  s16x8 v8 = *(const s16x8*)&p[c0];
  float f[8];
  float s = 0.f, s2 = 0.f;
#pragma unroll
  for (int i = 0; i < 8; i++) {
    float xv = bf2f((unsigned short)v8[i]);
    f[i] = xv; s += xv; s2 += xv * xv;
  }
#pragma unroll
  for (int d = 1; d < 64; d <<= 1) { s += __shfl_xor(s, d); s2 += __shfl_xor(s2, d); }
  float mu = s * (1.f / CDIM);
  float var = s2 * (1.f / CDIM) - mu * mu;
  float rs = rsqrtf(var + 1e-5f);

  float4 g0 = *(const float4*)&gg[c0], g1 = *(const float4*)&gg[c0 + 4];
  float4 e0 = *(const float4*)&be[c0], e1 = *(const float4*)&be[c0 + 4];
  float gv[8] = {g0.x, g0.y, g0.z, g0.w, g1.x, g1.y, g1.z, g1.w};
  float ev[8] = {e0.x, e0.y, e0.z, e0.w, e1.x, e1.y, e1.z, e1.w};
  s16x8 o;
#pragma unroll
  for (int i = 0; i < 8; i++)
    o[i] = (short)f2bf((f[i] - mu) * rs * gv[i] + ev[i]);
  *(s16x8*)&p[c0] = o;
}

// ---------------- fused attention, swapped-operand, one block per (w,h) ------
// Barrier moved to just before PV (QK^T/softmax don't read VT).
__global__ __launch_bounds__(576) void attn_kernel(
    const unsigned short* __restrict__ qkv, const unsigned short* __restrict__ cmb,
    unsigned short* __restrict__ outp)
{
  __shared__ short VT[32 * 168];    // VT[d][key], keys 144..159 zeroed
  // chunked XCD swizzle: 16 heads of one window land on the same XCD
  const int nb = NWIN * NHEADS;
  const int lid = (blockIdx.x & 7) * (nb >> 3) + (blockIdx.x >> 3);
  const int w = lid >> 4, h = lid & 15;
  const int t = threadIdx.x;
  const unsigned short* qb = qkv + (size_t)w * NTOK * 1536;
  const int hq = h * 32;

  {  // stage V transposed
    const int n = t >> 2, d0 = (t & 3) * 8;
    s16x8 vv = *(const s16x8*)&qb[(size_t)n * 1536 + 1024 + hq + d0];
#pragma unroll
    for (int i = 0; i < 8; i++) VT[(d0 + i) * 168 + n] = vv[i];
  }
  if (t < 512) VT[(t >> 4) * 168 + 144 + (t & 15)] = 0;

  const int lane = t & 63, wv = t >> 6, lg = lane >> 4, lc = lane & 15;
  const int q = wv * 16 + lc;           // this lane's query row (window-local)
  const f32x4 zero = {0.f, 0.f, 0.f, 0.f};

  const s16x8 qf = *(const s16x8*)&qb[(size_t)q * 1536 + hq + lg * 8];

  const int cls = (w < 64) ? (w & 3) : 4 + ((w - 64) & 15);
  const unsigned short* cm =
      cmb + ((size_t)cls * NHEADS + h) * (NTOK * NTOK) + (size_t)q * NTOK;
  uint2 cmr[9];
#pragma unroll
  for (int nt = 0; nt < 9; nt++)
    cmr[nt] = *(const uint2*)&cm[nt * 16 + lg * 4];

  f32x4 accS[9];
#pragma unroll
  for (int nt = 0; nt < 9; nt++) {
    s16x8 kf = *(const s16x8*)&qb[(size_t)(nt * 16 + lc) * 1536 + 512 + hq + lg * 8];
    accS[nt] = __builtin_amdgcn_mfma_f32_16x16x32_bf16(kf, qf, zero, 0, 0, 0);
  }

  float mx = -1e30f;
#pragma unroll
  for (int nt = 0; nt < 9; nt++) {
    accS[nt][0] += bf2f((unsigned short)(cmr[nt].x & 0xffff));
    accS[nt][1] += bf2f((unsigned short)(cmr[nt].x >> 16));
    accS[nt][2] += bf2f((unsigned short)(cmr[nt].y & 0xffff));
    accS[nt][3] += bf2f((unsigned short)(cmr[nt].y >> 16));
#pragma unroll
    for (int r = 0; r < 4; r++) mx = fmaxf(mx, accS[nt][r]);
  }
  mx = fmaxf(mx, __shfl_xor(mx, 16));
  mx = fmaxf(mx, __shfl_xor(mx, 32));

  float sum = 0.f;
#pragma unroll
  for (int nt = 0; nt < 9; nt++)
#pragma unroll
    for (int r = 0; r < 4; r++) {
      float e = __expf(accS[nt][r] - mx);
      accS[nt][r] = e;
      sum += e;
    }
  sum += __shfl_xor(sum, 16);
  sum += __shfl_xor(sum, 32);
  const float inv = 1.f / sum;

  unsigned pk0[9], pk1[9];
#pragma unroll
  for (int nt = 0; nt < 9; nt++) {
    pk0[nt] = (unsigned)f2bf(accS[nt][0]) | ((unsigned)f2bf(accS[nt][1]) << 16);
    pk1[nt] = (unsigned)f2bf(accS[nt][2]) | ((unsigned)f2bf(accS[nt][3]) << 16);
  }

  __syncthreads();   // VT ready (V-store latency hidden under QK^T + softmax)

#pragma unroll
  for (int dt = 0; dt < 2; dt++) {
    const short* vbase = &VT[(dt * 16 + lc) * 168];
    f32x4 accO = zero;
#pragma unroll
    for (int kk = 0; kk < 4; kk++) {
      u32x2 A0 = *(const u32x2*)&vbase[32 * kk + lg * 4];
      u32x2 A1 = *(const u32x2*)&vbase[32 * kk + 16 + lg * 4];
      s16x8 a = mk8(A0[0], A0[1], A1[0], A1[1]);
      s16x8 b = mk8(pk0[2 * kk], pk1[2 * kk], pk0[2 * kk + 1], pk1[2 * kk + 1]);
      accO = __builtin_amdgcn_mfma_f32_16x16x32_bf16(a, b, accO, 0, 0, 0);
    }
    {
      u32x2 A0 = *(const u32x2*)&vbase[128 + lg * 4];
      s16x8 a = mk8(A0[0], A0[1], 0u, 0u);
      s16x8 b = mk8(pk0[8], pk1[8], 0u, 0u);
      accO = __builtin_amdgcn_mfma_f32_16x16x32_bf16(a, b, accO, 0, 0, 0);
    }
    unsigned o0 = (unsigned)f2bf(accO[0] * inv) | ((unsigned)f2bf(accO[1] * inv) << 16);
    unsigned o1 = (unsigned)f2bf(accO[2] * inv) | ((unsigned)f2bf(accO[3] * inv) << 16);
    uint2 st; st.x = o0; st.y = o1;
    *(uint2*)&outp[(size_t)(w * NTOK + q) * CDIM + hq + dt * 16 + lg * 4] = st;
  }
}

// ---------------- launch ----------------
extern "C" void kernel_launch(void* const* d_in, const int* in_sizes, int n_in,
                              void* d_out, int out_size, void* d_ws, size_t ws_size,
                              hipStream_t stream)
{
  const float* x     = (const float*)d_in[0];
  const float* tpl   = (const float*)d_in[1];
  const float* mask0 = (const float*)d_in[2];
  const float* mask1 = (const float*)d_in[3];
  const float* rpb   = (const float*)d_in[8];
  const float* w_ps  = (const float*)d_in[9];
  const float* b_ps  = (const float*)d_in[10];
  const float* g_ps  = (const float*)d_in[11];
  const float* be_ps = (const float*)d_in[12];
  const float* w_pt  = (const float*)d_in[13];
  const float* b_pt  = (const float*)d_in[14];
  const float* g_pt  = (const float*)d_in[15];
  const float* be_pt = (const float*)d_in[16];
  const float* w_qkv = (const float*)d_in[17];
  const float* b_qkv = (const float*)d_in[18];
  const float* w_tr  = (const float*)d_in[19];
  const float* b_tr  = (const float*)d_in[20];
  const float* w_sr  = (const float*)d_in[21];
  const float* b_sr  = (const float*)d_in[22];

  // ws layout (~236MB of 720MiB):
  char* ws = (char*)d_ws;
  unsigned short* wpsT  = (unsigned short*)(ws + 0x0000000);  // 1MB
  unsigned short* wptT  = (unsigned short*)(ws + 0x0100000);  // 1MB
  unsigned short* wqkvT = (unsigned short*)(ws + 0x0200000);  // 1.5MB (Q-scaled)
  unsigned short* wtrT  = (unsigned short*)(ws + 0x0380000);  // 1MB
  unsigned short* wsrT  = (unsigned short*)(ws + 0x0480000);  // 1MB [0x480000,0x580000)
  unsigned short* cmb   = (unsigned short*)(ws + 0x0580000);  // 12.7MB -> ends ~0x1228000
  float* bqS            = (float*)(ws + 0x12F0000);           // 6KB scaled b_qkv (free gap)
  unsigned short* xa    = (unsigned short*)(ws + 0x1300000);  // 47.2MB [46080][512]
  unsigned short* Sa    = (unsigned short*)(ws + 0x4000000);  // 94.4MB cast-A (union
  unsigned short* qkvF  = (unsigned short*)(ws + 0x4000000);  //  w/ 141.6MB qkv)
  float* outb           = (float*)d_out;

  transpose_cast<<<2048, 256, 0, stream>>>(w_ps, wpsT, 1024, 512, 0, 1.f);
  transpose_cast<<<2048, 256, 0, stream>>>(w_pt, wptT, 1024, 512, 0, 1.f);
  transpose_cast<<<3072, 256, 0, stream>>>(w_qkv, wqkvT, 512, 1536,
                                           512, 0.17677669529663687f);
  transpose_cast<<<2048, 256, 0, stream>>>(w_tr, wtrT, 512, 1024, 0, 1.f);
  transpose_cast<<<2048, 256, 0, stream>>>(w_sr, wsrT, 512, 1024, 0, 1.f);
  scale_bias<<<6, 256, 0, stream>>>(b_qkv, bqS);
  build_cmb<<<(NCLS * NHEADS * NTOK * NTOK + 255) / 256, 256, 0, stream>>>(rpb, mask0, mask1, cmb);

  // cast inputs to bf16: tpl -> Sa[0:9216), x -> Sa[9216:46080)
  cast_bf16<<<(TROWS * 1024 / 8 + 255) / 256, 256, 0, stream>>>(tpl, Sa, TROWS * 1024 / 8);
  cast_bf16<<<(SROWS * 1024 / 8 + 255) / 256, 256, 0, stream>>>(
      x, Sa + (size_t)TROWS * 1024, SROWS * 1024 / 8);

  // projection GEMM (merged template+search) -> xa bf16
  gemm_glds<0><<<dim3(4, 360), 256, 0, stream>>>(Sa, wptT, wpsT, b_pt, b_ps,
                                                 xa, TOTROWS, CDIM, 1024);
  // LayerNorm in place on xa
  ln_kernel<<<TOTROWS / 4, 256, 0, stream>>>(xa, g_pt, be_pt, g_ps, be_ps);

  // QKV GEMM (Q-scale folded into weights/bias) -> qkvF (overwrites dead Sa)
  gemm_glds<0><<<dim3(12, 360), 256, 0, stream>>>(xa, wqkvT, wqkvT, bqS, bqS,
                                                  qkvF, TOTROWS, 1536, CDIM);
  // fused attention (one dispatch) -> xa
  attn_kernel<<<NWIN * NHEADS, 576, 0, stream>>>(qkvF, cmb, xa);

  // output GEMM (merged) -> d_out f32
  gemm_glds<2><<<dim3(8, 360), 256, 0, stream>>>(xa, wtrT, wsrT, b_tr, b_sr,
                                                 outb, TOTROWS, 1024, CDIM);
}

// Round 15
// 461.929 us; speedup vs baseline: 1.1714x; 1.0231x over previous
//
#include <hip/hip_runtime.h>

// MixingAttention on MI355X (gfx950) — ROUND 15.
// 1) Counted vmcnt in GEMM dbuf loop (T4): s_waitcnt vmcnt(8) + raw barrier
//    instead of full drain; trailing barrier guards buffer reuse.
// 2) Cast pass deleted: proj GEMM (gemm_f32a, BM=64) stages f32 A via
//    global_load_lds (16-granule XOR swizzle) and converts with
//    v_cvt_pk_bf16_f32 at fragment read. A-traffic 377 -> 189 MB.

using s16x8 = __attribute__((ext_vector_type(8))) short;   // 8 bf16
using f32x4 = __attribute__((ext_vector_type(4))) float;   // 4 f32 acc
typedef __attribute__((ext_vector_type(2))) unsigned u32x2;

#define NTOK 144
#define NHEADS 16
#define CDIM 512
#define TROWS 9216
#define SROWS 36864
#define TOTROWS 46080
#define NWIN 320
#define NCLS 20

__device__ __forceinline__ unsigned short f2bf(float f) {
  unsigned u = __float_as_uint(f);
  u += 0x7fffu + ((u >> 16) & 1u);     // RNE
  return (unsigned short)(u >> 16);
}
__device__ __forceinline__ float bf2f(unsigned short u) {
  return __uint_as_float(((unsigned)u) << 16);
}
__device__ __forceinline__ s16x8 mk8(unsigned a, unsigned b, unsigned c, unsigned d) {
  union { unsigned u[4]; s16x8 v; } x;
  x.u[0] = a; x.u[1] = b; x.u[2] = c; x.u[3] = d;
  return x.v;
}
__device__ __forceinline__ unsigned pkbf(float a, float b) {
  unsigned r;
  asm("v_cvt_pk_bf16_f32 %0, %1, %2" : "=v"(r) : "v"(a), "v"(b));
  return r;   // lo = bf16(a), hi = bf16(b), RNE
}

// async global->LDS, 16B per lane; lds base wave-uniform.
__device__ __forceinline__ void gld16(const void* g, void* l) {
  __builtin_amdgcn_global_load_lds(
      (const __attribute__((address_space(1))) unsigned int*)g,
      (__attribute__((address_space(3))) unsigned int*)l, 16, 0, 0);
}

// ---------------- prep kernels ----------------

__global__ void transpose_cast(const float* __restrict__ w,
                               unsigned short* __restrict__ wT, int Kd, int Nd,
                               int nScale, float s) {
  int i = blockIdx.x * 256 + threadIdx.x;
  if (i >= Kd * Nd) return;
  int n = i / Kd, k = i % Kd;
  float v = w[(size_t)k * Nd + n];
  if (n < nScale) v *= s;
  wT[i] = f2bf(v);
}

__global__ void scale_bias(const float* __restrict__ in, float* __restrict__ out) {
  int i = blockIdx.x * 256 + threadIdx.x;
  if (i >= 1536) return;
  out[i] = in[i] * (i < 512 ? 0.17677669529663687f : 1.0f);
}

__global__ void build_cmb(const float* __restrict__ rpb, const float* __restrict__ m0,
                          const float* __restrict__ m1, unsigned short* __restrict__ cmb) {
  int i = blockIdx.x * 256 + threadIdx.x;
  if (i >= NCLS * NHEADS * NTOK * NTOK) return;
  int cls = i / (NHEADS * NTOK * NTOK);
  int rem = i % (NHEADS * NTOK * NTOK);
  int h = rem / (NTOK * NTOK);
  int ij = rem % (NTOK * NTOK);
  int qi = ij / NTOK, kj = ij % NTOK;
  int dh = qi / 12 - kj / 12 + 11;
  int dw = qi % 12 - kj % 12 + 11;
  float bias = rpb[(dh * 23 + dw) * NHEADS + h];
  float mv = (cls < 4) ? m1[(size_t)cls * NTOK * NTOK + ij]
                       : m0[(size_t)(cls - 4) * NTOK * NTOK + ij];
  cmb[i] = f2bf(bias + mv);
}

// ---------------- bf16 GEMM: BK=64, swizzle, dbuf, counted vmcnt ----------
// EPI 0: +bias, bf16.  EPI 2: +bias, f32.
template<int EPI>
__global__ __launch_bounds__(256) void gemm_glds(
    const unsigned short* __restrict__ Ab,
    const unsigned short* __restrict__ BTt, const unsigned short* __restrict__ BTs,
    const float* __restrict__ biast, const float* __restrict__ biass,
    void* __restrict__ Cout, int M, int N, int K)
{
  __shared__ short As[2][128 * 64];
  __shared__ short Bs[2][128 * 64];
  const int t = threadIdx.x;
  const int lane = t & 63, wv = t >> 6, lg = lane >> 4, lc = lane & 15;

  const int id = blockIdx.x + gridDim.x * blockIdx.y;
  const int chunk = (gridDim.x * gridDim.y) >> 3;
  const int lid = (id & 7) * chunk + (id >> 3);
  const int bn = (lid % gridDim.x) * 128, bm = (lid / gridDim.x) * 128;

  const bool isT = bm < TROWS;
  const unsigned short* BT = isT ? BTt : BTs;
  const float* bias = isT ? biast : biass;

  const int srow = 32 * wv + (lane >> 3);
  const int scol = ((lane & 7) ^ ((lane >> 3) & 7)) * 8;
  const unsigned short* aSrc = Ab + (size_t)(bm + srow) * K + scol;
  const unsigned short* bSrc = BT + (size_t)(bn + srow) * K + scol;
  const size_t rowK8 = (size_t)8 * K;

  f32x4 acc[2][8] = {};

  auto STAGE = [&](int b, int kt) {
#pragma unroll
    for (int i = 0; i < 4; i++) {
      gld16(aSrc + kt + i * rowK8, &As[b][(wv * 4 + i) * 512]);
      gld16(bSrc + kt + i * rowK8, &Bs[b][(wv * 4 + i) * 512]);
    }
  };
  auto COMPUTE = [&](int b) {
#pragma unroll
    for (int kk = 0; kk < 2; kk++) {
      const int csw = 8 * ((4 * kk + lg) ^ (lc & 7));
      const int r0 = wv * 32 + lc, r1 = r0 + 16;
      s16x8 a0 = *(const s16x8*)&As[b][r0 * 64 + csw];
      s16x8 a1 = *(const s16x8*)&As[b][r1 * 64 + csw];
#pragma unroll
      for (int nt = 0; nt < 8; nt++) {
        s16x8 bfr = *(const s16x8*)&Bs[b][(nt * 16 + lc) * 64 + csw];
        acc[0][nt] = __builtin_amdgcn_mfma_f32_16x16x32_bf16(a0, bfr, acc[0][nt], 0, 0, 0);
        acc[1][nt] = __builtin_amdgcn_mfma_f32_16x16x32_bf16(a1, bfr, acc[1][nt], 0, 0, 0);
      }
    }
  };

  STAGE(0, 0);
  int cur = 0;
  for (int kt = 64; kt < K; kt += 64) {
    STAGE(cur ^ 1, kt);                       // 8 loads in flight (next tile)
    asm volatile("s_waitcnt vmcnt(8)" ::: "memory");   // prev tile retired
    __builtin_amdgcn_s_barrier();             // all waves' stages visible
    __builtin_amdgcn_sched_barrier(0);
    COMPUTE(cur);
    __builtin_amdgcn_s_barrier();             // reads done before buf reuse
    cur ^= 1;
  }
  asm volatile("s_waitcnt vmcnt(0)" ::: "memory");
  __builtin_amdgcn_s_barrier();
  __builtin_amdgcn_sched_barrier(0);
  COMPUTE(cur);

#pragma unroll
  for (int mt = 0; mt < 2; mt++) {
    const int rbase = bm + wv * 32 + mt * 16 + lg * 4;
#pragma unroll
    for (int nt = 0; nt < 8; nt++) {
      const int cg = bn + nt * 16 + lc;
#pragma unroll
      for (int r = 0; r < 4; r++) {
        const int rg = rbase + r;
        float val = acc[mt][nt][r] + bias[cg];
        if (EPI == 2) ((float*)Cout)[(size_t)rg * N + cg] = val;
        else ((unsigned short*)Cout)[(size_t)rg * N + cg] = f2bf(val);
      }
    }
  }
}

// ---------------- f32-A GEMM (projection): BM=64, BK=64 ----------
// A staged as f32 via gload_lds; LDS granule (16B=4 f32) p holds global
// granule p ^ (row&15); fragment read converts with v_cvt_pk_bf16_f32.
__global__ __launch_bounds__(256) void gemm_f32a(
    const float* __restrict__ At, const float* __restrict__ Asrch,
    const unsigned short* __restrict__ BTt, const unsigned short* __restrict__ BTs,
    const float* __restrict__ biast, const float* __restrict__ biass,
    unsigned short* __restrict__ Cout, int M, int N, int K)
{
  __shared__ float Asf[2][64 * 64];   // 2 x 16KB... (64 rows x 64 f32 = 16KB) x2
  __shared__ short Bs[2][128 * 64];   // 2 x 16KB
  const int t = threadIdx.x;
  const int lane = t & 63, wv = t >> 6, lg = lane >> 4, lc = lane & 15;

  const int id = blockIdx.x + gridDim.x * blockIdx.y;
  const int chunk = (gridDim.x * gridDim.y) >> 3;
  const int lid = (id & 7) * chunk + (id >> 3);
  const int bn = (lid % gridDim.x) * 128, bm = (lid / gridDim.x) * 64;

  const bool isT = bm < TROWS;
  const float* Af = isT ? At : (Asrch - (size_t)TROWS * K);
  const unsigned short* BT = isT ? BTt : BTs;
  const float* bias = isT ? biast : biass;

  // A staging: instr i (0..3) covers rows wv*16 + i*4 + (l>>4);
  // source granule (4 f32) = (l&15) ^ (row&15), row&15 = (i*4 + (l>>4)) & 15.
  const int arow = wv * 16 + (lane >> 4);
  // B staging: rows 32wv + i*8 + (l>>3), granule (l&7)^((l>>3)&7)
  const int brow = 32 * wv + (lane >> 3);
  const int bcol = ((lane & 7) ^ ((lane >> 3) & 7)) * 8;
  const unsigned short* bSrc = BT + (size_t)(bn + brow) * K + bcol;
  const size_t rowK8 = (size_t)8 * K;

  f32x4 acc[8] = {};

  auto STAGE = [&](int b, int kt) {
#pragma unroll
    for (int i = 0; i < 4; i++) {
      const int r = arow + i * 4;
      const int sg = ((lane & 15) ^ (r & 15)) * 4;
      gld16(Af + (size_t)(bm + r) * K + kt + sg, &Asf[b][(wv * 16 + i * 4) * 64]);
      gld16(bSrc + kt + i * rowK8, &Bs[b][(wv * 4 + i) * 512]);
    }
  };
  auto COMPUTE = [&](int b) {
#pragma unroll
    for (int kk = 0; kk < 2; kk++) {
      const int G0 = 2 * (4 * kk + lg);
      const int r0 = wv * 16 + lc;
      const float* arowp = &Asf[b][r0 * 64];
      float4 x0 = *(const float4*)&arowp[(G0 ^ lc) * 4];
      float4 x1 = *(const float4*)&arowp[((G0 + 1) ^ lc) * 4];
      s16x8 a0 = mk8(pkbf(x0.x, x0.y), pkbf(x0.z, x0.w),
                     pkbf(x1.x, x1.y), pkbf(x1.z, x1.w));
      const int csw = 8 * ((4 * kk + lg) ^ (lc & 7));
#pragma unroll
      for (int nt = 0; nt < 8; nt++) {
        s16x8 bfr = *(const s16x8*)&Bs[b][(nt * 16 + lc) * 64 + csw];
        acc[nt] = __builtin_amdgcn_mfma_f32_16x16x32_bf16(a0, bfr, acc[nt], 0, 0, 0);
      }
    }
  };

  STAGE(0, 0);
  int cur = 0;
  for (int kt = 64; kt < K; kt += 64) {
    STAGE(cur ^ 1, kt);
    asm volatile("s_waitcnt vmcnt(8)" ::: "memory");
    __builtin_amdgcn_s_barrier();
    __builtin_amdgcn_sched_barrier(0);
    COMPUTE(cur);
    __builtin_amdgcn_s_barrier();
    cur ^= 1;
  }
  asm volatile("s_waitcnt vmcnt(0)" ::: "memory");
  __builtin_amdgcn_s_barrier();
  __builtin_amdgcn_sched_barrier(0);
  COMPUTE(cur);

  const int rbase = bm + wv * 16 + lg * 4;
#pragma unroll
  for (int nt = 0; nt < 8; nt++) {
    const int cg = bn + nt * 16 + lc;
#pragma unroll
    for (int r = 0; r < 4; r++)
      Cout[(size_t)(rbase + r) * N + cg] = f2bf(acc[nt][r] + bias[cg]);
  }
}

// ---------------- LayerNorm, in place (wave per row) ----------------
__global__ __launch_bounds__(256) void ln_kernel(
    unsigned short* __restrict__ xa,
    const float* __restrict__ g_pt, const float* __restrict__ be_pt,
    const float* __restrict__ g_ps, const float* __restrict__ be_ps)
{
  const int row = blockIdx.x * 4 + (threadIdx.x >> 6);
  const int lane = threadIdx.x & 63;
  const bool isT = row < TROWS;
  const float* gg = isT ? g_pt : g_ps;
  const float* be = isT ? be_pt : be_ps;
  unsigned short* p = xa + (size_t)row * CDIM;
  const int c0 = lane * 8;

  s16x8 v8 = *(const s16x8*)&p[c0];
  float f[8];
  float s = 0.f, s2 = 0.f;
#pragma unroll
  for (int i = 0; i < 8; i++) {
    float xv = bf2f((unsigned short)v8[i]);
    f[i] = xv; s += xv; s2 += xv * xv;
  }
#pragma unroll
  for (int d = 1; d < 64; d <<= 1) { s += __shfl_xor(s, d); s2 += __shfl_xor(s2, d); }
  float mu = s * (1.f / CDIM);
  float var = s2 * (1.f / CDIM) - mu * mu;
  float rs = rsqrtf(var + 1e-5f);

  float4 g0 = *(const float4*)&gg[c0], g1 = *(const float4*)&gg[c0 + 4];
  float4 e0 = *(const float4*)&be[c0], e1 = *(const float4*)&be[c0 + 4];
  float gv[8] = {g0.x, g0.y, g0.z, g0.w, g1.x, g1.y, g1.z, g1.w};
  float ev[8] = {e0.x, e0.y, e0.z, e0.w, e1.x, e1.y, e1.z, e1.w};
  s16x8 o;
#pragma unroll
  for (int i = 0; i < 8; i++)
    o[i] = (short)f2bf((f[i] - mu) * rs * gv[i] + ev[i]);
  *(s16x8*)&p[c0] = o;
}

// ---------------- fused attention (unchanged from r14) ----------------
__global__ __launch_bounds__(576) void attn_kernel(
    const unsigned short* __restrict__ qkv, const unsigned short* __restrict__ cmb,
    unsigned short* __restrict__ outp)
{
  __shared__ short VT[32 * 168];
  const int nb = NWIN * NHEADS;
  const int lid = (blockIdx.x & 7) * (nb >> 3) + (blockIdx.x >> 3);
  const int w = lid >> 4, h = lid & 15;
  const int t = threadIdx.x;
  const unsigned short* qb = qkv + (size_t)w * NTOK * 1536;
  const int hq = h * 32;

  {
    const int n = t >> 2, d0 = (t & 3) * 8;
    s16x8 vv = *(const s16x8*)&qb[(size_t)n * 1536 + 1024 + hq + d0];
#pragma unroll
    for (int i = 0; i < 8; i++) VT[(d0 + i) * 168 + n] = vv[i];
  }
  if (t < 512) VT[(t >> 4) * 168 + 144 + (t & 15)] = 0;

  const int lane = t & 63, wv = t >> 6, lg = lane >> 4, lc = lane & 15;
  const int q = wv * 16 + lc;
  const f32x4 zero = {0.f, 0.f, 0.f, 0.f};

  const s16x8 qf = *(const s16x8*)&qb[(size_t)q * 1536 + hq + lg * 8];

  const int cls = (w < 64) ? (w & 3) : 4 + ((w - 64) & 15);
  const unsigned short* cm =
      cmb + ((size_t)cls * NHEADS + h) * (NTOK * NTOK) + (size_t)q * NTOK;
  uint2 cmr[9];
#pragma unroll
  for (int nt = 0; nt < 9; nt++)
    cmr[nt] = *(const uint2*)&cm[nt * 16 + lg * 4];

  f32x4 accS[9];
#pragma unroll
  for (int nt = 0; nt < 9; nt++) {
    s16x8 kf = *(const s16x8*)&qb[(size_t)(nt * 16 + lc) * 1536 + 512 + hq + lg * 8];
    accS[nt] = __builtin_amdgcn_mfma_f32_16x16x32_bf16(kf, qf, zero, 0, 0, 0);
  }

  float mx = -1e30f;
#pragma unroll
  for (int nt = 0; nt < 9; nt++) {
    accS[nt][0] += bf2f((unsigned short)(cmr[nt].x & 0xffff));
    accS[nt][1] += bf2f((unsigned short)(cmr[nt].x >> 16));
    accS[nt][2] += bf2f((unsigned short)(cmr[nt].y & 0xffff));
    accS[nt][3] += bf2f((unsigned short)(cmr[nt].y >> 16));
#pragma unroll
    for (int r = 0; r < 4; r++) mx = fmaxf(mx, accS[nt][r]);
  }
  mx = fmaxf(mx, __shfl_xor(mx, 16));
  mx = fmaxf(mx, __shfl_xor(mx, 32));

  float sum = 0.f;
#pragma unroll
  for (int nt = 0; nt < 9; nt++)
#pragma unroll
    for (int r = 0; r < 4; r++) {
      float e = __expf(accS[nt][r] - mx);
      accS[nt][r] = e;
      sum += e;
    }
  sum += __shfl_xor(sum, 16);
  sum += __shfl_xor(sum, 32);
  const float inv = 1.f / sum;

  unsigned pk0[9], pk1[9];
#pragma unroll
  for (int nt = 0; nt < 9; nt++) {
    pk0[nt] = (unsigned)f2bf(accS[nt][0]) | ((unsigned)f2bf(accS[nt][1]) << 16);
    pk1[nt] = (unsigned)f2bf(accS[nt][2]) | ((unsigned)f2bf(accS[nt][3]) << 16);
  }

  __syncthreads();

#pragma unroll
  for (int dt = 0; dt < 2; dt++) {
    const short* vbase = &VT[(dt * 16 + lc) * 168];
    f32x4 accO = zero;
#pragma unroll
    for (int kk = 0; kk < 4; kk++) {
      u32x2 A0 = *(const u32x2*)&vbase[32 * kk + lg * 4];
      u32x2 A1 = *(const u32x2*)&vbase[32 * kk + 16 + lg * 4];
      s16x8 a = mk8(A0[0], A0[1], A1[0], A1[1]);
      s16x8 b = mk8(pk0[2 * kk], pk1[2 * kk], pk0[2 * kk + 1], pk1[2 * kk + 1]);
      accO = __builtin_amdgcn_mfma_f32_16x16x32_bf16(a, b, accO, 0, 0, 0);
    }
    {
      u32x2 A0 = *(const u32x2*)&vbase[128 + lg * 4];
      s16x8 a = mk8(A0[0], A0[1], 0u, 0u);
      s16x8 b = mk8(pk0[8], pk1[8], 0u, 0u);
      accO = __builtin_amdgcn_mfma_f32_16x16x32_bf16(a, b, accO, 0, 0, 0);
    }
    unsigned o0 = (unsigned)f2bf(accO[0] * inv) | ((unsigned)f2bf(accO[1] * inv) << 16);
    unsigned o1 = (unsigned)f2bf(accO[2] * inv) | ((unsigned)f2bf(accO[3] * inv) << 16);
    uint2 st; st.x = o0; st.y = o1;
    *(uint2*)&outp[(size_t)(w * NTOK + q) * CDIM + hq + dt * 16 + lg * 4] = st;
  }
}

// ---------------- launch ----------------
extern "C" void kernel_launch(void* const* d_in, const int* in_sizes, int n_in,
                              void* d_out, int out_size, void* d_ws, size_t ws_size,
                              hipStream_t stream)
{
  const float* x     = (const float*)d_in[0];
  const float* tpl   = (const float*)d_in[1];
  const float* mask0 = (const float*)d_in[2];
  const float* mask1 = (const float*)d_in[3];
  const float* rpb   = (const float*)d_in[8];
  const float* w_ps  = (const float*)d_in[9];
  const float* b_ps  = (const float*)d_in[10];
  const float* g_ps  = (const float*)d_in[11];
  const float* be_ps = (const float*)d_in[12];
  const float* w_pt  = (const float*)d_in[13];
  const float* b_pt  = (const float*)d_in[14];
  const float* g_pt  = (const float*)d_in[15];
  const float* be_pt = (const float*)d_in[16];
  const float* w_qkv = (const float*)d_in[17];
  const float* b_qkv = (const float*)d_in[18];
  const float* w_tr  = (const float*)d_in[19];
  const float* b_tr  = (const float*)d_in[20];
  const float* w_sr  = (const float*)d_in[21];
  const float* b_sr  = (const float*)d_in[22];

  char* ws = (char*)d_ws;
  unsigned short* wpsT  = (unsigned short*)(ws + 0x0000000);
  unsigned short* wptT  = (unsigned short*)(ws + 0x0100000);
  unsigned short* wqkvT = (unsigned short*)(ws + 0x0200000);
  unsigned short* wtrT  = (unsigned short*)(ws + 0x0380000);
  unsigned short* wsrT  = (unsigned short*)(ws + 0x0480000);
  unsigned short* cmb   = (unsigned short*)(ws + 0x0580000);
  float* bqS            = (float*)(ws + 0x12F0000);
  unsigned short* xa    = (unsigned short*)(ws + 0x1300000);
  unsigned short* qkvF  = (unsigned short*)(ws + 0x4000000);
  float* outb           = (float*)d_out;

  transpose_cast<<<2048, 256, 0, stream>>>(w_ps, wpsT, 1024, 512, 0, 1.f);
  transpose_cast<<<2048, 256, 0, stream>>>(w_pt, wptT, 1024, 512, 0, 1.f);
  transpose_cast<<<3072, 256, 0, stream>>>(w_qkv, wqkvT, 512, 1536,
                                           512, 0.17677669529663687f);
  transpose_cast<<<2048, 256, 0, stream>>>(w_tr, wtrT, 512, 1024, 0, 1.f);
  transpose_cast<<<2048, 256, 0, stream>>>(w_sr, wsrT, 512, 1024, 0, 1.f);
  scale_bias<<<6, 256, 0, stream>>>(b_qkv, bqS);
  build_cmb<<<(NCLS * NHEADS * NTOK * NTOK + 255) / 256, 256, 0, stream>>>(rpb, mask0, mask1, cmb);

  // projection GEMM, f32 A consumed directly (no cast pass) -> xa bf16
  gemm_f32a<<<dim3(4, 720), 256, 0, stream>>>(tpl, x, wptT, wpsT, b_pt, b_ps,
                                              xa, TOTROWS, CDIM, 1024);
  // LayerNorm in place on xa
  ln_kernel<<<TOTROWS / 4, 256, 0, stream>>>(xa, g_pt, be_pt, g_ps, be_ps);

  // QKV GEMM (Q-scale folded) -> qkvF
  gemm_glds<0><<<dim3(12, 360), 256, 0, stream>>>(xa, wqkvT, wqkvT, bqS, bqS,
                                                  qkvF, TOTROWS, 1536, CDIM);
  // fused attention -> xa
  attn_kernel<<<NWIN * NHEADS, 576, 0, stream>>>(qkvF, cmb, xa);

  // output GEMM -> d_out f32
  gemm_glds<2><<<dim3(8, 360), 256, 0, stream>>>(xa, wtrT, wsrT, b_tr, b_sr,
                                                 outb, TOTROWS, 1024, CDIM);
}